// Round 1
// baseline (134.302 us; speedup 1.0000x reference)
//
#include <hip/hip_runtime.h>
#include <hip/hip_cooperative_groups.h>

namespace cg = cooperative_groups;

#define NB 8192
#define ND 128
#define NC 100
#define MARGIN_F 0.3f

#define NBLK 1024            // 4 blocks per CU -> co-resident (max 8), 4 waves/SIMD
#define WAVES_PB 4           // 256 threads
// 1024 blocks * 4 waves * 2 rows = 8192 rows

// Fused: stage-1 partial per block, grid-wide barrier, block 0 reduces 1024
// partials. Single dispatch replaces the old 2-kernel pipeline.
__global__ __launch_bounds__(256) void triplet_fused_kernel(
    const float* __restrict__ inputs,   // (NB, ND) fp32
    const int*   __restrict__ targets,  // (NB,) int32
    const int*   __restrict__ ixs,      // (NB, 2) int32
    const float* __restrict__ brdf,     // (NC, NC) fp32
    float*       __restrict__ partial,  // (NBLK,) in workspace
    float*       __restrict__ out)      // (1,)
{
    const int wave = threadIdx.x >> 6;
    const int lane = threadIdx.x & 63;
    const int sub  = lane >> 5;          // which of 2 rows in this wave
    const int sl   = lane & 31;          // slot within the row (32 lanes/row)
    const int wave_id = blockIdx.x * WAVES_PB + wave;   // 0..4095
    const int row = wave_id * 2 + sub;                  // 0..8191

    const int i0 = ixs[2 * row];
    const int i1 = ixs[2 * row + 1];

    // 32 lanes * float4 = 128 floats = full row, coalesced dwordx4.
    const float4* xr = (const float4*)(inputs + (size_t)row * ND);
    const float4* xa = (const float4*)(inputs + (size_t)i0  * ND);
    const float4* xb = (const float4*)(inputs + (size_t)i1  * ND);

    float4 r = xr[sl];
    float4 a = xa[sl];
    float4 b = xb[sl];

    float da, db, t;
    t = r.x - a.x; da  = t * t;
    t = r.y - a.y; da += t * t;
    t = r.z - a.z; da += t * t;
    t = r.w - a.w; da += t * t;

    t = r.x - b.x; db  = t * t;
    t = r.y - b.y; db += t * t;
    t = r.z - b.z; db += t * t;
    t = r.w - b.w; db += t * t;

    // 5-step butterfly confined to each 32-lane group
    #pragma unroll
    for (int off = 1; off <= 16; off <<= 1) {
        da += __shfl_xor(da, off, 64);
        db += __shfl_xor(db, off, 64);
    }

    float acc = 0.0f;
    if (sl == 0) {   // lanes 0 and 32: finish their row
        float d0 = sqrtf(fmaxf(da, 1e-12f));
        float d1 = sqrtf(fmaxf(db, 1e-12f));
        int tt = targets[row];
        int t0 = targets[i0];
        int t1 = targets[i1];
        float md1 = brdf[tt * NC + t0];
        float md2 = brdf[tt * NC + t1];
        float diff = (md1 < md2) ? (d0 - d1) : (d1 - d0);
        acc = fmaxf(diff + MARGIN_F, 0.0f);
    }
    acc += __shfl_xor(acc, 32, 64);   // lanes 0+32 -> lane 0

    __shared__ float wsum[WAVES_PB];
    if (lane == 0) wsum[wave] = acc;
    __syncthreads();
    if (threadIdx.x == 0) {
        partial[blockIdx.x] = wsum[0] + wsum[1] + wsum[2] + wsum[3];
        __threadfence();   // make the partial visible device-wide before the barrier
    }

    cg::this_grid().sync();

    // Tail: block 0 reduces the 1024 partials (same shape as old stage 2).
    if (blockIdx.x == 0) {
        float4 v = ((const float4*)partial)[threadIdx.x];   // 256 * 4 = 1024
        float s = (v.x + v.y) + (v.z + v.w);

        #pragma unroll
        for (int off = 1; off <= 32; off <<= 1)
            s += __shfl_xor(s, off, 64);

        if (lane == 0) wsum[wave] = s;
        __syncthreads();
        if (threadIdx.x == 0)
            out[0] = (wsum[0] + wsum[1] + wsum[2] + wsum[3]) * (1.0f / (float)NB);
    }
}

extern "C" void kernel_launch(void* const* d_in, const int* in_sizes, int n_in,
                              void* d_out, int out_size, void* d_ws, size_t ws_size,
                              hipStream_t stream) {
    const float* inputs  = (const float*)d_in[0];
    const int*   targets = (const int*)d_in[1];
    const int*   ixs     = (const int*)d_in[2];
    const float* brdf    = (const float*)d_in[3];
    float* out     = (float*)d_out;
    float* partial = (float*)d_ws;    // 1024 floats of scratch

    void* args[] = { (void*)&inputs, (void*)&targets, (void*)&ixs,
                     (void*)&brdf,   (void*)&partial, (void*)&out };
    hipLaunchCooperativeKernel(reinterpret_cast<const void*>(triplet_fused_kernel),
                               dim3(NBLK), dim3(256), args, 0, stream);
}

// Round 2
// 64.751 us; speedup vs baseline: 2.0741x; 2.0741x over previous
//
#include <hip/hip_runtime.h>

#define NB 8192
#define ND 128
#define NC 100
#define MARGIN_F 0.3f

#define NBLK1 2048           // stage-1 blocks: 8 per CU -> 8 waves/SIMD (100% occ cap)
#define WAVES_PB 4           // 256 threads
// 2048 blocks * 4 waves = 8192 waves, 1 row per wave

// Stage 1: 64 lanes per row (float2 each), 1 row per wave; block partial -> partial[blockIdx]
__global__ __launch_bounds__(256) void triplet_partial_kernel(
    const float* __restrict__ inputs,   // (NB, ND) fp32
    const int*   __restrict__ targets,  // (NB,) int32
    const int*   __restrict__ ixs,      // (NB, 2) int32
    const float* __restrict__ brdf,     // (NC, NC) fp32
    float*       __restrict__ partial)  // (NBLK1,)
{
    const int wave = threadIdx.x >> 6;
    const int lane = threadIdx.x & 63;
    const int row  = blockIdx.x * WAVES_PB + wave;      // 0..8191

    // one 8B load for both indices
    const int2 ii = ((const int2*)ixs)[row];
    const int i0 = ii.x;
    const int i1 = ii.y;

    // 64 lanes * float2 = 128 floats = full row, coalesced 512B per load.
    const float2* xr = (const float2*)(inputs + (size_t)row * ND);
    const float2* xa = (const float2*)(inputs + (size_t)i0  * ND);
    const float2* xb = (const float2*)(inputs + (size_t)i1  * ND);

    float2 r = xr[lane];
    float2 a = xa[lane];
    float2 b = xb[lane];

    // brdf chain hoisted: same-address broadcast loads on all lanes, overlaps
    // the row loads and the butterfly instead of serializing after them.
    const int tt = targets[row];
    const int t0 = targets[i0];
    const int t1 = targets[i1];
    const float md1 = brdf[tt * NC + t0];
    const float md2 = brdf[tt * NC + t1];

    float da, db, t;
    t = r.x - a.x; da  = t * t;
    t = r.y - a.y; da += t * t;
    t = r.x - b.x; db  = t * t;
    t = r.y - b.y; db += t * t;

    // 6-step butterfly across the full 64-lane wave
    #pragma unroll
    for (int off = 1; off <= 32; off <<= 1) {
        da += __shfl_xor(da, off, 64);
        db += __shfl_xor(db, off, 64);
    }

    float acc = 0.0f;
    if (lane == 0) {
        float d0 = sqrtf(fmaxf(da, 1e-12f));
        float d1 = sqrtf(fmaxf(db, 1e-12f));
        float diff = (md1 < md2) ? (d0 - d1) : (d1 - d0);
        acc = fmaxf(diff + MARGIN_F, 0.0f);
    }

    __shared__ float wsum[WAVES_PB];
    if (lane == 0) wsum[wave] = acc;
    __syncthreads();
    if (threadIdx.x == 0)
        partial[blockIdx.x] = wsum[0] + wsum[1] + wsum[2] + wsum[3];
}

// Stage 2: one block of 512 threads reduces 2048 partials; overwrites out.
__global__ __launch_bounds__(512) void triplet_reduce_kernel(
    const float* __restrict__ partial,
    float*       __restrict__ out)
{
    const int wave = threadIdx.x >> 6;
    const int lane = threadIdx.x & 63;

    float4 v = ((const float4*)partial)[threadIdx.x];   // 512 * 4 = 2048
    float s = (v.x + v.y) + (v.z + v.w);

    #pragma unroll
    for (int off = 1; off <= 32; off <<= 1)
        s += __shfl_xor(s, off, 64);

    __shared__ float wsum[8];
    if (lane == 0) wsum[wave] = s;
    __syncthreads();
    if (threadIdx.x == 0) {
        float r = 0.0f;
        #pragma unroll
        for (int w = 0; w < 8; ++w) r += wsum[w];
        out[0] = r * (1.0f / (float)NB);
    }
}

extern "C" void kernel_launch(void* const* d_in, const int* in_sizes, int n_in,
                              void* d_out, int out_size, void* d_ws, size_t ws_size,
                              hipStream_t stream) {
    const float* inputs  = (const float*)d_in[0];
    const int*   targets = (const int*)d_in[1];
    const int*   ixs     = (const int*)d_in[2];
    const float* brdf    = (const float*)d_in[3];
    float* out     = (float*)d_out;
    float* partial = (float*)d_ws;    // 2048 floats of scratch

    triplet_partial_kernel<<<NBLK1, 256, 0, stream>>>(inputs, targets, ixs, brdf, partial);
    triplet_reduce_kernel<<<1, 512, 0, stream>>>(partial, out);
}